// Round 7
// baseline (174.710 us; speedup 1.0000x reference)
//
#include <hip/hip_runtime.h>
#include <hip/hip_bf16.h>
#include <math.h>

#define OUT0   2097152      // 4*1024*512 (output 0 size)
#define SP_EPS 1e-7f
#define CEXP   0.18033688011112042f   // 0.125 * log2(e): exp(s/8) == exp2(s*CEXP)

typedef __attribute__((ext_vector_type(8))) short bf16x8;
typedef __attribute__((ext_vector_type(4))) float f32x4;

// ---------------- bf16 split helpers (RN-to-nearest-even) ------------------
__device__ __forceinline__ unsigned short f2bf(float f) {
  unsigned int b = __float_as_uint(f);
  return (unsigned short)((b + 0x7fffu + ((b >> 16) & 1u)) >> 16);
}
__device__ __forceinline__ float bf2f(unsigned short u) {
  return __uint_as_float(((unsigned int)u) << 16);
}

// ---------------- kernel Z: zero-fill the attn region (128 MB) -------------
__global__ __launch_bounds__(256) void zerofill_kernel(float4* __restrict__ p, int n4) {
  const int stride = gridDim.x * 256;
  for (int i = blockIdx.x * 256 + threadIdx.x; i < n4; i += stride)
    p[i] = make_float4(0.f, 0.f, 0.f, 0.f);
}

// ---------------- kernel 0: split-convert up to 3 weight matrices ----------
__global__ __launch_bounds__(256) void convW_kernel(
    const float* __restrict__ w0, const float* __restrict__ w1,
    const float* __restrict__ w2, unsigned short* __restrict__ dst)
{
  const int z = blockIdx.z;
  const float* src = (z == 0) ? w0 : (z == 1) ? w1 : w2;
  unsigned short* hi = dst + (size_t)z * (1u << 19);
  unsigned short* lo = hi + (1u << 18);
  const int i = (blockIdx.x * 256 + threadIdx.x) * 4;
  const float4 x = *(const float4*)(src + i);
  ushort4 h, l;
  h.x = f2bf(x.x); l.x = f2bf(x.x - bf2f(h.x));
  h.y = f2bf(x.y); l.y = f2bf(x.y - bf2f(h.y));
  h.z = f2bf(x.z); l.z = f2bf(x.z - bf2f(h.z));
  h.w = f2bf(x.w); l.w = f2bf(x.w - bf2f(h.w));
  *(ushort4*)(hi + i) = h;
  *(ushort4*)(lo + i) = l;
}

// ---------------- kernel 1: QKV projection via split-bf16 MFMA -------------
__global__ __launch_bounds__(256) void qkv_mfma_kernel(
    const float* __restrict__ q, const float* __restrict__ k, const float* __restrict__ v,
    const unsigned short* __restrict__ Wsplit,
    const float* __restrict__ bq, const float* __restrict__ bk, const float* __restrict__ bv,
    unsigned short* __restrict__ qhh, unsigned short* __restrict__ qhl,
    unsigned short* __restrict__ khh, unsigned short* __restrict__ khl,
    float* __restrict__ vh)
{
  __shared__ short Ash[64 * 64], Asl[64 * 64];
  __shared__ short Bsh[128 * 64], Bsl[128 * 64];
  const int z = blockIdx.z;
  const float* A = (z == 0) ? q : (z == 1) ? k : v;
  const unsigned short* Wh = Wsplit + (size_t)z * (1u << 19);
  const unsigned short* Wl = Wh + (1u << 18);
  const float* bias = (z == 0) ? bq : (z == 1) ? bk : bv;
  const int r0 = blockIdx.x * 64, n0 = blockIdx.y * 128;
  const int tid = threadIdx.x, lane = tid & 63, w = tid >> 6;
  const int wr = w >> 1, wc = w & 1;
  const int l15 = lane & 15, l4 = lane >> 4;

  f32x4 acc[2][4];
#pragma unroll
  for (int a = 0; a < 2; ++a)
#pragma unroll
    for (int b = 0; b < 4; ++b) acc[a][b] = (f32x4){0.f, 0.f, 0.f, 0.f};

  for (int kt = 0; kt < 8; ++kt) {
    __syncthreads();
#pragma unroll
    for (int p = 0; p < 2; ++p) {
      const int c = tid + p * 256, row = c >> 3, k8 = (c & 7) * 8;
      const float4 x0 = *(const float4*)(A + (size_t)(r0 + row) * 512 + kt * 64 + k8);
      const float4 x1 = *(const float4*)(A + (size_t)(r0 + row) * 512 + kt * 64 + k8 + 4);
      bf16x8 hv, lv;
      const float xs[8] = {x0.x, x0.y, x0.z, x0.w, x1.x, x1.y, x1.z, x1.w};
#pragma unroll
      for (int j = 0; j < 8; ++j) {
        const unsigned short h = f2bf(xs[j]);
        hv[j] = (short)h; lv[j] = (short)f2bf(xs[j] - bf2f(h));
      }
      const int si = row * 64 + (k8 ^ ((row & 7) << 3));
      *(bf16x8*)&Ash[si] = hv; *(bf16x8*)&Asl[si] = lv;
    }
#pragma unroll
    for (int p = 0; p < 4; ++p) {
      const int c = tid + p * 256, row = c >> 3, k8 = (c & 7) * 8;
      const size_t go = (size_t)(n0 + row) * 512 + kt * 64 + k8;
      const int si = row * 64 + (k8 ^ ((row & 7) << 3));
      *(bf16x8*)&Bsh[si] = *(const bf16x8*)(Wh + go);
      *(bf16x8*)&Bsl[si] = *(const bf16x8*)(Wl + go);
    }
    __syncthreads();
#pragma unroll
    for (int kf = 0; kf < 2; ++kf) {
      const int kb = kf * 32 + l4 * 8;
      bf16x8 ah[2], al2[2];
#pragma unroll
      for (int rb = 0; rb < 2; ++rb) {
        const int ar = wr * 32 + rb * 16 + l15;
        const int si = ar * 64 + (kb ^ ((ar & 7) << 3));
        ah[rb] = *(bf16x8*)&Ash[si]; al2[rb] = *(bf16x8*)&Asl[si];
      }
#pragma unroll
      for (int cb = 0; cb < 4; ++cb) {
        const int br = wc * 64 + cb * 16 + l15;
        const int si = br * 64 + (kb ^ ((br & 7) << 3));
        const bf16x8 bh = *(bf16x8*)&Bsh[si];
        const bf16x8 bl = *(bf16x8*)&Bsl[si];
#pragma unroll
        for (int rb = 0; rb < 2; ++rb) {
          acc[rb][cb] = __builtin_amdgcn_mfma_f32_16x16x32_bf16(al2[rb], bh, acc[rb][cb], 0, 0, 0);
          acc[rb][cb] = __builtin_amdgcn_mfma_f32_16x16x32_bf16(ah[rb], bl, acc[rb][cb], 0, 0, 0);
          acc[rb][cb] = __builtin_amdgcn_mfma_f32_16x16x32_bf16(ah[rb], bh, acc[rb][cb], 0, 0, 0);
        }
      }
    }
  }
  unsigned short* H = (z == 0) ? qhh : khh;
  unsigned short* L = (z == 0) ? qhl : khl;
#pragma unroll
  for (int cb = 0; cb < 4; ++cb) {
    const int col = n0 + wc * 64 + cb * 16 + l15;
    const float bia = bias[col];
    const int h = col >> 6, d = col & 63;
#pragma unroll
    for (int rb = 0; rb < 2; ++rb)
#pragma unroll
      for (int ri = 0; ri < 4; ++ri) {
        const int row = r0 + wr * 32 + rb * 16 + l4 * 4 + ri;
        const int b = row >> 10, ll = row & 1023;
        const size_t idx = ((size_t)(h * 4 + b) << 16) + (ll << 6) + d;
        const float val = acc[rb][cb][ri] + bia;
        if (z == 2) {
          vh[idx] = val;
        } else {
          const unsigned short hv = f2bf(val);
          H[idx] = hv;
          L[idx] = f2bf(val - bf2f(hv));
        }
      }
  }
}

// ---------------- kernel 2: sparse attention, two-sweep, scatter-only ------
// Block: 64 q-rows x all 1024 kv of one bh; 4 waves, 16 rows each.
// Pass 1: stream K-tiles (16 kv, LDS dbuf), 6 MFMA/tile, online {m, Z, top6}
//   per (lane, ri); merge across the 16-lane row group (butterfly).
// Pass 2: recompute scores bit-identically; survivors (u > u6+EPS*Z) are
//   collected per row (<=5), scattered into pre-zeroed attn; then PV + split.
__global__ __launch_bounds__(256) void sparse_attn_kernel(
    const unsigned short* __restrict__ qhh, const unsigned short* __restrict__ qhl,
    const unsigned short* __restrict__ khh, const unsigned short* __restrict__ khl,
    const float* __restrict__ vh, float* __restrict__ attn,
    unsigned short* __restrict__ ofhi, unsigned short* __restrict__ oflo)
{
  __shared__ short Kh[2][16 * 64], Kl[2][16 * 64];
  __shared__ float s_w[4][16][8];
  __shared__ int   s_i[4][16][8];
  __shared__ int   s_n[4][16];
  const int bh = blockIdx.y;
  const int r0 = blockIdx.x * 64;
  const int tid = threadIdx.x, lane = tid & 63, wvid = tid >> 6;
  const int l15 = lane & 15, l4 = lane >> 4;
  const size_t base = (size_t)bh << 16;

  // Q fragments for this wave's 16 rows (live through both passes)
  bf16x8 qh8[2], ql8[2];
#pragma unroll
  for (int kf = 0; kf < 2; ++kf) {
    const size_t qa = base + (size_t)(r0 + wvid * 16 + l15) * 64 + kf * 32 + l4 * 8;
    qh8[kf] = *(const bf16x8*)(qhh + qa);
    ql8[kf] = *(const bf16x8*)(qhl + qa);
  }

  // staging geometry: 256 threads cover 16 rows x 64 elems x {hi,lo} in 16B chunks
  const int s_which = tid >> 7;
  const int s_rem = tid & 127;
  const int s_row = s_rem >> 3, s_k8 = (s_rem & 7) * 8;
  const int s_si = s_row * 64 + (s_k8 ^ ((s_row & 7) << 3));
  const unsigned short* s_src = (s_which ? khl : khh) + base + s_row * 64 + s_k8;

  // read-side fragment LDS offsets
  const int si0 = l15 * 64 + ((l4 * 8) ^ ((l15 & 7) << 3));
  const int si1 = l15 * 64 + ((32 + l4 * 8) ^ ((l15 & 7) << 3));

  // ---- pass 1: online m, Z, top-6 ----
  float m0 = -3e38f, m1 = -3e38f, m2 = -3e38f, m3 = -3e38f;
  float Z0 = 0.f, Z1 = 0.f, Z2 = 0.f, Z3 = 0.f;
  float t[4][6];
#pragma unroll
  for (int ri = 0; ri < 4; ++ri)
#pragma unroll
    for (int j = 0; j < 6; ++j) t[ri][j] = -3e38f;

  { const bf16x8 v0 = *(const bf16x8*)s_src;
    if (s_which) *(bf16x8*)&Kl[0][s_si] = v0; else *(bf16x8*)&Kh[0][s_si] = v0; }

  for (int kt = 0; kt < 64; ++kt) {
    __syncthreads();
    const int cur = kt & 1;
    bf16x8 nxt;
    if (kt < 63) nxt = *(const bf16x8*)(s_src + (kt + 1) * 1024);
    f32x4 acc = (f32x4){0.f, 0.f, 0.f, 0.f};
#pragma unroll
    for (int kf = 0; kf < 2; ++kf) {
      const int si = kf ? si1 : si0;
      const bf16x8 kh8 = *(bf16x8*)&Kh[cur][si];
      const bf16x8 kl8 = *(bf16x8*)&Kl[cur][si];
      acc = __builtin_amdgcn_mfma_f32_16x16x32_bf16(ql8[kf], kh8, acc, 0, 0, 0);
      acc = __builtin_amdgcn_mfma_f32_16x16x32_bf16(qh8[kf], kl8, acc, 0, 0, 0);
      acc = __builtin_amdgcn_mfma_f32_16x16x32_bf16(qh8[kf], kh8, acc, 0, 0, 0);
    }
#pragma unroll
    for (int ri = 0; ri < 4; ++ri) {
      const float d = acc[ri];
      float* mp = (ri == 0) ? &m0 : (ri == 1) ? &m1 : (ri == 2) ? &m2 : &m3;
      float* zp = (ri == 0) ? &Z0 : (ri == 1) ? &Z1 : (ri == 2) ? &Z2 : &Z3;
      const float nm = fmaxf(*mp, d);
      *zp = *zp * exp2f((*mp - nm) * CEXP) + exp2f((d - nm) * CEXP);
      *mp = nm;
      float v = d;
#pragma unroll
      for (int j = 0; j < 6; ++j) {
        const float a = fmaxf(t[ri][j], v);
        v = fminf(t[ri][j], v);
        t[ri][j] = a;
      }
    }
    if (kt < 63) {
      if (s_which) *(bf16x8*)&Kl[cur ^ 1][s_si] = nxt;
      else         *(bf16x8*)&Kh[cur ^ 1][s_si] = nxt;
    }
  }

  // ---- merge across the 16-lane row group ----
  float mC[4], u6p[4], inv[4], Zm[4];
  float mA[4] = {m0, m1, m2, m3};
  float ZA[4] = {Z0, Z1, Z2, Z3};
#pragma unroll
  for (int ri = 0; ri < 4; ++ri) {
    const float ml = mA[ri];
    float mg = ml;
#pragma unroll
    for (int off = 1; off < 16; off <<= 1) mg = fmaxf(mg, __shfl_xor(mg, off));
    float zz = ZA[ri] * exp2f((ml - mg) * CEXP);
#pragma unroll
    for (int off = 1; off < 16; off <<= 1) zz += __shfl_xor(zz, off);
    float t0 = t[ri][0], t1 = t[ri][1], t2 = t[ri][2],
          t3 = t[ri][3], t4 = t[ri][4], t5 = t[ri][5];
#pragma unroll
    for (int off = 1; off < 16; off <<= 1) {
      const float b0 = __shfl_xor(t0, off), b1 = __shfl_xor(t1, off),
                  b2 = __shfl_xor(t2, off), b3 = __shfl_xor(t3, off),
                  b4 = __shfl_xor(t4, off), b5 = __shfl_xor(t5, off);
      float n0 = fmaxf(t0, b5), n1 = fmaxf(t1, b4), n2 = fmaxf(t2, b3),
            n3 = fmaxf(t3, b2), n4 = fmaxf(t4, b1), n5 = fmaxf(t5, b0);
      float a;
      a = fmaxf(n0, n3); n3 = fminf(n0, n3); n0 = a;
      a = fmaxf(n1, n4); n4 = fminf(n1, n4); n1 = a;
      a = fmaxf(n2, n5); n5 = fminf(n2, n5); n2 = a;
      a = fmaxf(n0, n1); n1 = fminf(n0, n1); n0 = a;
      a = fmaxf(n0, n2); n2 = fminf(n0, n2); n0 = a;
      a = fmaxf(n1, n2); n2 = fminf(n1, n2); n1 = a;
      a = fmaxf(n3, n4); n4 = fminf(n3, n4); n3 = a;
      a = fmaxf(n3, n5); n5 = fminf(n3, n5); n3 = a;
      a = fmaxf(n4, n5); n5 = fminf(n4, n5); n4 = a;
      t0 = n0; t1 = n1; t2 = n2; t3 = n3; t4 = n4; t5 = n5;
    }
    const float mCg = mg * CEXP;
    const float u6 = exp2f(fmaf(t5, CEXP, -mCg));
    const float u6x = u6 + SP_EPS * zz;
    float Ss = 0.f;
    Ss += fmaxf(exp2f(fmaf(t0, CEXP, -mCg)) - u6x, 0.f);
    Ss += fmaxf(exp2f(fmaf(t1, CEXP, -mCg)) - u6x, 0.f);
    Ss += fmaxf(exp2f(fmaf(t2, CEXP, -mCg)) - u6x, 0.f);
    Ss += fmaxf(exp2f(fmaf(t3, CEXP, -mCg)) - u6x, 0.f);
    Ss += fmaxf(exp2f(fmaf(t4, CEXP, -mCg)) - u6x, 0.f);
    mC[ri] = mCg; u6p[ri] = u6x; Zm[ri] = zz;
    inv[ri] = 1.0f / (Ss + SP_EPS * zz);
  }

  // zero survivor slots (fixed-trip PV loop later reads all 5)
  {
    float* pw = &s_w[wvid][0][0];
    int*   pi = &s_i[wvid][0][0];
    pw[lane] = 0.f; pw[lane + 64] = 0.f;
    pi[lane] = 0;   pi[lane + 64] = 0;
  }

  // ---- pass 2: recompute, collect survivors ----
  int cnt[4] = {0, 0, 0, 0};
  { const bf16x8 v0 = *(const bf16x8*)s_src;
    if (s_which) *(bf16x8*)&Kl[0][s_si] = v0; else *(bf16x8*)&Kh[0][s_si] = v0; }

  for (int kt = 0; kt < 64; ++kt) {
    __syncthreads();
    const int cur = kt & 1;
    bf16x8 nxt;
    if (kt < 63) nxt = *(const bf16x8*)(s_src + (kt + 1) * 1024);
    f32x4 acc = (f32x4){0.f, 0.f, 0.f, 0.f};
#pragma unroll
    for (int kf = 0; kf < 2; ++kf) {
      const int si = kf ? si1 : si0;
      const bf16x8 kh8 = *(bf16x8*)&Kh[cur][si];
      const bf16x8 kl8 = *(bf16x8*)&Kl[cur][si];
      acc = __builtin_amdgcn_mfma_f32_16x16x32_bf16(ql8[kf], kh8, acc, 0, 0, 0);
      acc = __builtin_amdgcn_mfma_f32_16x16x32_bf16(qh8[kf], kl8, acc, 0, 0, 0);
      acc = __builtin_amdgcn_mfma_f32_16x16x32_bf16(qh8[kf], kh8, acc, 0, 0, 0);
    }
#pragma unroll
    for (int ri = 0; ri < 4; ++ri) {
      const float u = exp2f(fmaf(acc[ri], CEXP, -mC[ri]));
      const float wv = u - u6p[ri];
      const unsigned long long mask = __ballot(wv > 0.f);
      if (mask) {
        const unsigned sub = (unsigned)(mask >> (l4 * 16)) & 0xFFFFu;
        if (sub) {
          if (wv > 0.f) {
            const int pos = cnt[ri] + __popc(sub & ((1u << l15) - 1u));
            if (pos < 8) {
              s_w[wvid][l4 * 4 + ri][pos] = wv * inv[ri];
              s_i[wvid][l4 * 4 + ri][pos] = kt * 16 + l15;
            }
          }
          cnt[ri] += __popc(sub);
        }
      }
    }
    if (kt < 63) {
      if (s_which) *(bf16x8*)&Kl[cur ^ 1][s_si] = nxt;
      else         *(bf16x8*)&Kh[cur ^ 1][s_si] = nxt;
    }
  }

  if (l15 == 0) {
#pragma unroll
    for (int ri = 0; ri < 4; ++ri) s_n[wvid][l4 * 4 + ri] = cnt[ri];
  }

  // ---- PV + attn scatter + out_full split write ----
  float accv[16];
#pragma unroll
  for (int r = 0; r < 16; ++r) accv[r] = 0.f;
  const float* vb = vh + base;
  float* arow = attn + ((size_t)bh << 20) + ((size_t)(r0 + wvid * 16) << 10);
#pragma unroll
  for (int tt = 0; tt < 5; ++tt) {
#pragma unroll
    for (int r = 0; r < 16; ++r) {
      const float wgt = s_w[wvid][r][tt];
      const int kvi = s_i[wvid][r][tt];
      accv[r] = fmaf(wgt, vb[(size_t)kvi * 64 + lane], accv[r]);
      if (lane == 0 && wgt > 0.f) arow[(size_t)r * 1024 + kvi] = wgt;
    }
  }
  const int b_ = bh & 3, h = bh >> 2;
#pragma unroll
  for (int r = 0; r < 16; ++r) {
    const int lq = r0 + wvid * 16 + r;
    const int idx = (((b_ << 10) | lq) << 9) + (h << 6) + lane;
    const unsigned short hv = f2bf(accv[r]);
    ofhi[idx] = hv;
    oflo[idx] = f2bf(accv[r] - bf2f(hv));
  }
}

// ---------------- kernel 3: fc+gate via split-bf16 MFMA + fused epilogue ---
__global__ __launch_bounds__(256) void out_proj_mfma_kernel(
    const unsigned short* __restrict__ ofhi, const unsigned short* __restrict__ oflo,
    const unsigned short* __restrict__ FG,
    const float* __restrict__ bfc, const float* __restrict__ bg,
    float* __restrict__ out)
{
  __shared__ short Ash[64 * 64], Asl[64 * 64];
  __shared__ short Bfh[128 * 64], Bfl[128 * 64];
  __shared__ short Bgh[128 * 64], Bgl[128 * 64];
  const unsigned short* Wfh = FG;
  const unsigned short* Wfl = FG + (1u << 18);
  const unsigned short* Wgh = FG + (2u << 18);
  const unsigned short* Wgl = FG + 3u * (1u << 18);
  const int r0 = blockIdx.x * 64, n0 = blockIdx.y * 128;
  const int tid = threadIdx.x, lane = tid & 63, w = tid >> 6;
  const int wr = w >> 1, wc = w & 1;
  const int l15 = lane & 15, l4 = lane >> 4;

  f32x4 accf[2][4], accg[2][4];
#pragma unroll
  for (int a = 0; a < 2; ++a)
#pragma unroll
    for (int b = 0; b < 4; ++b) {
      accf[a][b] = (f32x4){0.f, 0.f, 0.f, 0.f};
      accg[a][b] = (f32x4){0.f, 0.f, 0.f, 0.f};
    }

  for (int kt = 0; kt < 8; ++kt) {
    __syncthreads();
#pragma unroll
    for (int p = 0; p < 2; ++p) {
      const int c = tid + p * 256, row = c >> 3, k8 = (c & 7) * 8;
      const size_t go = (size_t)(r0 + row) * 512 + kt * 64 + k8;
      const int si = row * 64 + (k8 ^ ((row & 7) << 3));
      *(bf16x8*)&Ash[si] = *(const bf16x8*)(ofhi + go);
      *(bf16x8*)&Asl[si] = *(const bf16x8*)(oflo + go);
    }
#pragma unroll
    for (int p = 0; p < 4; ++p) {
      const int c = tid + p * 256, row = c >> 3, k8 = (c & 7) * 8;
      const int si = row * 64 + (k8 ^ ((row & 7) << 3));
      const size_t go = (size_t)(n0 + row) * 512 + kt * 64 + k8;
      *(bf16x8*)&Bfh[si] = *(const bf16x8*)(Wfh + go);
      *(bf16x8*)&Bfl[si] = *(const bf16x8*)(Wfl + go);
      *(bf16x8*)&Bgh[si] = *(const bf16x8*)(Wgh + go);
      *(bf16x8*)&Bgl[si] = *(const bf16x8*)(Wgl + go);
    }
    __syncthreads();
#pragma unroll
    for (int kf = 0; kf < 2; ++kf) {
      const int kb = kf * 32 + l4 * 8;
      bf16x8 ah[2], al2[2];
#pragma unroll
      for (int rb = 0; rb < 2; ++rb) {
        const int ar = wr * 32 + rb * 16 + l15;
        const int si = ar * 64 + (kb ^ ((ar & 7) << 3));
        ah[rb] = *(bf16x8*)&Ash[si]; al2[rb] = *(bf16x8*)&Asl[si];
      }
#pragma unroll
      for (int cb = 0; cb < 4; ++cb) {
        const int br = wc * 64 + cb * 16 + l15;
        const int si = br * 64 + (kb ^ ((br & 7) << 3));
        const bf16x8 fh = *(bf16x8*)&Bfh[si];
        const bf16x8 fl = *(bf16x8*)&Bfl[si];
        const bf16x8 gh = *(bf16x8*)&Bgh[si];
        const bf16x8 gl = *(bf16x8*)&Bgl[si];
#pragma unroll
        for (int rb = 0; rb < 2; ++rb) {
          accf[rb][cb] = __builtin_amdgcn_mfma_f32_16x16x32_bf16(al2[rb], fh, accf[rb][cb], 0, 0, 0);
          accf[rb][cb] = __builtin_amdgcn_mfma_f32_16x16x32_bf16(ah[rb], fl, accf[rb][cb], 0, 0, 0);
          accf[rb][cb] = __builtin_amdgcn_mfma_f32_16x16x32_bf16(ah[rb], fh, accf[rb][cb], 0, 0, 0);
          accg[rb][cb] = __builtin_amdgcn_mfma_f32_16x16x32_bf16(al2[rb], gh, accg[rb][cb], 0, 0, 0);
          accg[rb][cb] = __builtin_amdgcn_mfma_f32_16x16x32_bf16(ah[rb], gl, accg[rb][cb], 0, 0, 0);
          accg[rb][cb] = __builtin_amdgcn_mfma_f32_16x16x32_bf16(ah[rb], gh, accg[rb][cb], 0, 0, 0);
        }
      }
    }
  }
#pragma unroll
  for (int cb = 0; cb < 4; ++cb) {
    const int col = n0 + wc * 64 + cb * 16 + l15;
    const float bf4 = bfc[col];
    const float bg4 = bg[col];
#pragma unroll
    for (int rb = 0; rb < 2; ++rb)
#pragma unroll
      for (int ri = 0; ri < 4; ++ri) {
        const int row = r0 + wr * 32 + rb * 16 + l4 * 4 + ri;
        const float f = accf[rb][cb][ri] + bf4;
        const float g = accg[rb][cb][ri] + bg4;
        out[(size_t)row * 512 + col] = tanhf(f) / (1.f + __expf(-g));
      }
  }
}

extern "C" void kernel_launch(void* const* d_in, const int* in_sizes, int n_in,
                              void* d_out, int out_size, void* d_ws, size_t ws_size,
                              hipStream_t stream) {
  const float* q   = (const float*)d_in[0];
  const float* k   = (const float*)d_in[1];
  const float* v   = (const float*)d_in[2];
  const float* Wq  = (const float*)d_in[3];
  const float* bq  = (const float*)d_in[4];
  const float* Wk  = (const float*)d_in[5];
  const float* bk  = (const float*)d_in[6];
  const float* Wv  = (const float*)d_in[7];
  const float* bv  = (const float*)d_in[8];
  const float* Wfc = (const float*)d_in[9];
  const float* bfc = (const float*)d_in[10];
  const float* Wg  = (const float*)d_in[11];
  const float* bg  = (const float*)d_in[12];

  float* out  = (float*)d_out;
  float* attn = out + OUT0;                 // (32,1024,1024) final output 1

  // qh splits live in the out0 region (8MB, overwritten by out_proj at the end)
  unsigned short* qhh = (unsigned short*)d_out;
  unsigned short* qhl = qhh + (1u << 21);

  // ws (24MB): [0,8M) khh/khl -> later FG; [8,16M) vh; [16M..) Wqkv -> ofhi/oflo
  char* wsb = (char*)d_ws;
  unsigned short* khh  = (unsigned short*)wsb;
  unsigned short* khl  = (unsigned short*)(wsb + (4u << 20));
  float*          vh   = (float*)(wsb + (8u << 20));
  unsigned short* Wqkv = (unsigned short*)(wsb + (16u << 20));
  unsigned short* ofhi = (unsigned short*)(wsb + (16u << 20));
  unsigned short* oflo = (unsigned short*)(wsb + (20u << 20));
  unsigned short* FG   = (unsigned short*)wsb;

  zerofill_kernel<<<dim3(2048), 256, 0, stream>>>((float4*)attn, 1 << 23);
  convW_kernel<<<dim3(256, 1, 3), 256, 0, stream>>>(Wq, Wk, Wv, Wqkv);
  qkv_mfma_kernel<<<dim3(64, 4, 3), 256, 0, stream>>>(q, k, v, Wqkv, bq, bk, bv,
                                                      qhh, qhl, khh, khl, vh);
  sparse_attn_kernel<<<dim3(16, 32), 256, 0, stream>>>(qhh, qhl, khh, khl, vh,
                                                       attn, ofhi, oflo);
  convW_kernel<<<dim3(256, 1, 2), 256, 0, stream>>>(Wfc, Wg, Wg, FG);
  out_proj_mfma_kernel<<<dim3(64, 4), 256, 0, stream>>>(ofhi, oflo, FG, bfc, bg, out);
}